// Round 11
// baseline (1584.301 us; speedup 1.0000x reference)
//
#include <hip/hip_runtime.h>
#include <math.h>

#define NB 512           // grid blocks; 2/CU guaranteed at <=256 VGPR -> all co-resident
#define WPITCH 140       // LDS pitch (dwords) per capsule row of W tile

typedef __attribute__((ext_vector_type(8))) short bfrag;    // 8 bf16 = 4 VGPR
typedef __attribute__((ext_vector_type(4))) float f32x4;    // 16x16 accumulator
typedef __attribute__((ext_vector_type(16))) float f32x16;  // 32x32 accumulator

// split 8 f32 into bf16 hi + bf16 lo; 3-term MFMA (hh+hl+lh) ~ fp32 precision.
__device__ __forceinline__ void split8(const float* x, bfrag& hi, bfrag& lo) {
    #pragma unroll
    for (int j = 0; j < 8; ++j) {
        unsigned xb = __float_as_uint(x[j]);
        unsigned hb = xb & 0xffff0000u;
        float lf = x[j] - __uint_as_float(hb);
        hi[j] = (short)(xb >> 16);
        lo[j] = (short)(__float_as_uint(lf) >> 16);
    }
}

// grid barrier: counter slot k (zeroed by hipMemsetAsync each launch).
// __syncthreads drains all block VMEM (compiler emits vmcnt(0) before s_barrier);
// release-add publishes, acquire-spin observes, __threadfence (agent acq_rel)
// invalidates L1 so post-barrier reads see other XCDs' data.
__device__ __forceinline__ void gbar(int* cnt, int k) {
    __syncthreads();
    if (threadIdx.x == 0) {
        __hip_atomic_fetch_add(cnt + k, 1, __ATOMIC_RELEASE, __HIP_MEMORY_SCOPE_AGENT);
        while (__hip_atomic_load(cnt + k, __ATOMIC_ACQUIRE, __HIP_MEMORY_SCOPE_AGENT) < NB)
            __builtin_amdgcn_s_sleep(2);
    }
    __syncthreads();
    __threadfence();
}

// ---------------- spass phase: s_part[it][b][o][16] = sum_{96 caps} c*(W@u)
template <bool UNIFORM>
__device__ __forceinline__ void spass_phase(
    const float* W_lds, const float* u2, const float* blog,
    const float* m_, const float* z_, float* s_part,
    int o, int it, int wv, int q, int r16) {
    int i0 = it * 96;
    f32x4 acc0 = {0.f, 0.f, 0.f, 0.f};
    f32x4 acc1 = {0.f, 0.f, 0.f, 0.f};
    float4 ua[3][2][2];
    float blv[3][2], mv[3][2], zv[3][2];
    auto issue = [&](int s, int buf) {
        int cap = i0 + s * 4 + q;
        #pragma unroll
        for (int m = 0; m < 2; ++m) {
            int b = wv * 32 + m * 16 + r16;
            ua[buf][m][0] = *(const float4*)(u2 + ((size_t)(cap * 2 + 0) * 128 + b) * 4);
            ua[buf][m][1] = *(const float4*)(u2 + ((size_t)(cap * 2 + 1) * 128 + b) * 4);
            if (!UNIFORM) {
                blv[buf][m] = blog[((size_t)o * 768 + cap) * 128 + b];
                mv[buf][m]  = m_[cap * 128 + b];
                zv[buf][m]  = z_[cap * 128 + b];
            }
        }
    };
    issue(0, 0);
    issue(1, 1);
    #pragma unroll
    for (int s = 0; s < 24; ++s) {
        int cur = s % 3;
        if (s < 22) issue(s + 2, (s + 2) % 3);
        const float* wp = W_lds + (s * 4 + q) * WPITCH + r16 * 8;
        float wv8[8];
        *(float4*)(wv8) = *(const float4*)wp;
        *(float4*)(wv8 + 4) = *(const float4*)(wp + 4);
        bfrag bhi, blo;
        split8(wv8, bhi, blo);
        #pragma unroll
        for (int m = 0; m < 2; ++m) {
            float uv[8];
            *(float4*)(uv) = ua[cur][m][0];
            *(float4*)(uv + 4) = ua[cur][m][1];
            if (!UNIFORM) {
                float c = __expf(blv[cur][m] - mv[cur][m]) * zv[cur][m];
                #pragma unroll
                for (int j = 0; j < 8; ++j) uv[j] *= c;
            }
            bfrag ahi, alo;
            split8(uv, ahi, alo);
            if (m == 0) {
                acc0 = __builtin_amdgcn_mfma_f32_16x16x32_bf16(ahi, bhi, acc0, 0, 0, 0);
                acc0 = __builtin_amdgcn_mfma_f32_16x16x32_bf16(ahi, blo, acc0, 0, 0, 0);
                acc0 = __builtin_amdgcn_mfma_f32_16x16x32_bf16(alo, bhi, acc0, 0, 0, 0);
            } else {
                acc1 = __builtin_amdgcn_mfma_f32_16x16x32_bf16(ahi, bhi, acc1, 0, 0, 0);
                acc1 = __builtin_amdgcn_mfma_f32_16x16x32_bf16(ahi, blo, acc1, 0, 0, 0);
                acc1 = __builtin_amdgcn_mfma_f32_16x16x32_bf16(alo, bhi, acc1, 0, 0, 0);
            }
        }
    }
    #pragma unroll
    for (int reg = 0; reg < 4; ++reg) {
        int b0 = wv * 32 + q * 4 + reg;
        s_part[(((size_t)it * 128 + b0) * 64 + o) * 16 + r16] = acc0[reg];
        s_part[(((size_t)it * 128 + b0 + 16) * 64 + o) * 16 + r16] = acc1[reg];
    }
}

// ---------------- squashv phase: reduce 8 partials + squash
__device__ __forceinline__ void squashv_phase(
    const float* s_part, float* dst, float scale, bool transposed, int idx) {
    float acc = 0.f;
    #pragma unroll
    for (int p = 0; p < 8; ++p) acc += s_part[(size_t)p * 131072 + idx];
    acc *= scale;
    float n2 = acc * acc;
    n2 += __shfl_xor(n2, 1, 64);
    n2 += __shfl_xor(n2, 2, 64);
    n2 += __shfl_xor(n2, 4, 64);
    n2 += __shfl_xor(n2, 8, 64);
    float n = sqrtf(n2);
    float val = acc * n / (1.f + n2);
    if (transposed) {
        int k = idx & 15, o = (idx >> 4) & 63, b = idx >> 10;
        dst[((size_t)o * 128 + b) * 16 + k] = val;
    } else {
        dst[idx] = val;
    }
}

// ---------------- bpass phase: blog[o][cap][b] (+)= sum_d u * (W x v)
// A-frag read from spass-layout LDS (8 x b32, stride 8 dwords).
template <bool ACCUM>
__device__ __forceinline__ void bpass_phase(
    const float* W_lds, const float* u2, const float* v_t, float* blog,
    int o, int it, int wv, int l) {
    int r = l & 31;
    int kh = l >> 5;
    int capB = it * 96;
    bfrag vhi[4], vlo[4];
    #pragma unroll
    for (int nt = 0; nt < 4; ++nt) {
        const float* vp = v_t + ((size_t)o * 128 + nt * 32 + r) * 16 + kh * 8;
        float vv8[8];
        *(float4*)(vv8) = *(const float4*)vp;
        *(float4*)(vv8 + 4) = *(const float4*)(vp + 4);
        split8(vv8, vhi[nt], vlo[nt]);
    }
    #pragma unroll
    for (int mt = 0; mt < 6; ++mt) {
        int capg = capB + wv * 24 + mt * 4;
        float a8[8];
        const float* apb = W_lds + (size_t)(capg - capB + (r >> 3)) * WPITCH + (r & 7);
        #pragma unroll
        for (int j = 0; j < 8; ++j) a8[j] = apb[(kh * 8 + j) * 8];
        int gw = kh * 2;               // this half-wave writes g = gw, gw+1
        float prevv[4][2];
        if (ACCUM) {
            #pragma unroll
            for (int nt = 0; nt < 4; ++nt) {
                int b = nt * 32 + r;
                #pragma unroll
                for (int gg = 0; gg < 2; ++gg)
                    prevv[nt][gg] = blog[((size_t)o * 768 + capg + gw + gg) * 128 + b];
            }
        }
        float4 u4b[2][4];
        #pragma unroll
        for (int g = 0; g < 4; ++g)
            u4b[0][g] = *(const float4*)(u2 + ((size_t)((capg + g) * 2 + kh) * 128 + r) * 4);
        bfrag ahi, alo;
        split8(a8, ahi, alo);
        #pragma unroll
        for (int nt = 0; nt < 4; ++nt) {
            int cur = nt & 1;
            if (nt < 3) {
                int bn = (nt + 1) * 32 + r;
                #pragma unroll
                for (int g = 0; g < 4; ++g)
                    u4b[cur ^ 1][g] = *(const float4*)(u2 + ((size_t)((capg + g) * 2 + kh) * 128 + bn) * 4);
            }
            int b = nt * 32 + r;
            f32x16 acc;
            #pragma unroll
            for (int z = 0; z < 16; ++z) acc[z] = 0.f;
            acc = __builtin_amdgcn_mfma_f32_32x32x16_bf16(ahi, vhi[nt], acc, 0, 0, 0);
            acc = __builtin_amdgcn_mfma_f32_32x32x16_bf16(ahi, vlo[nt], acc, 0, 0, 0);
            acc = __builtin_amdgcn_mfma_f32_32x32x16_bf16(alo, vhi[nt], acc, 0, 0, 0);
            float full[4];
            #pragma unroll
            for (int g = 0; g < 4; ++g) {
                float part = u4b[cur][g].x * acc[g * 4 + 0] + u4b[cur][g].y * acc[g * 4 + 1]
                           + u4b[cur][g].z * acc[g * 4 + 2] + u4b[cur][g].w * acc[g * 4 + 3];
                full[g] = part + __shfl_xor(part, 32, 64);
            }
            #pragma unroll
            for (int gg = 0; gg < 2; ++gg) {
                int g = gw + gg;
                size_t bi = ((size_t)o * 768 + capg + g) * 128 + b;
                blog[bi] = (ACCUM ? prevv[nt][gg] : 0.f) + full[g];
            }
        }
    }
}

// ---------------- mz phase: softmax stats over o for capsule i, batch b
__device__ __forceinline__ void mz_phase(
    const float* blog, float* m_, float* z_, int i, int b) {
    const float* src = blog + (size_t)i * 128 + b;
    float r[64];
    float m = -1e30f;
    #pragma unroll
    for (int o = 0; o < 64; ++o) {
        r[o] = src[(size_t)o * 98304];
        m = fmaxf(m, r[o]);
    }
    float sum = 0.f;
    #pragma unroll
    for (int o = 0; o < 64; ++o) sum += __expf(r[o] - m);
    m_[i * 128 + b] = m;
    z_[i * 128 + b] = 1.f / sum;
}

// ================= persistent mega-kernel: all phases, grid barriers =================
__global__ __launch_bounds__(256, 2) void caps_mega(
    const float* __restrict__ x, const float* __restrict__ w1,
    const float* __restrict__ b1, const float* __restrict__ wp,
    const float* __restrict__ bp, const float* __restrict__ W,
    float* __restrict__ out, float* ws, int* cnt) {
    __shared__ float smem[96 * WPITCH];    // 53.8 KB: conv1 weights (P0) then W tile (P3+)
    int bid = blockIdx.x, tid = threadIdx.x;
    int wv = tid >> 6, l = tid & 63, q = l >> 4, r16 = l & 15;

    float* u2     = ws;
    float* blog   = ws + 786432;
    float* m_     = ws + 7077888;
    float* z_     = ws + 7176192;
    float* v      = ws + 7274496;
    float* s_part = ws + 7405568;          // 8 * 131072
    float* B2     = s_part;                // im2col output, dead before spass0
    float* h1     = ws + 8454144;

    // ---- P0: conv1
    for (int i = tid; i < 3456; i += 256) smem[i] = w1[i];
    __syncthreads();
    for (int idx = bid * 256 + tid; idx < 479232; idx += NB * 256) {
        int ow = idx % 13; int t = idx / 13;
        int oh = t % 9; t /= 9;
        int oc = t % 32; int b = t / 32;
        float acc = b1[oc];
        const float* xb = x + (size_t)b * 3 * 32 * 42;
        #pragma unroll
        for (int ic = 0; ic < 3; ++ic) {
            const float* xc = xb + ic * 1344 + (oh * 3) * 42 + ow * 3;
            const float* wc = smem + (oc * 3 + ic) * 36;
            #pragma unroll
            for (int kh = 0; kh < 6; ++kh)
                #pragma unroll
                for (int kw = 0; kw < 6; ++kw)
                    acc += xc[kh * 42 + kw] * wc[kh * 6 + kw];
        }
        h1[idx] = fmaxf(acc, 0.f);
    }
    gbar(cnt, 0);

    // ---- P1: im2col -> B2[ko][n][8]
    {
        int idx = bid * 256 + tid;
        if (idx < 110592) {
            int n = idx % 3072, ko = idx / 3072;
            int b = n / 24, s = n % 24, h = s / 6, w = s % 6;
            const float* hb = h1 + (size_t)b * 3744 + (2 * h) * 13 + 2 * w;
            float o8[8];
            #pragma unroll
            for (int j = 0; j < 8; ++j) {
                int k = ko * 8 + j;
                int ic = k / 9, rr = k % 9;
                int kh = rr / 3, kw = rr % 3;
                o8[j] = hb[ic * 117 + kh * 13 + kw];
            }
            *(float4*)(B2 + (size_t)idx * 8) = *(const float4*)o8;
            *(float4*)(B2 + (size_t)idx * 8 + 4) = *(const float4*)(o8 + 4);
        }
    }
    gbar(cnt, 1);

    // ---- P2: pc GEMM + bias + squash -> u2
    for (int lb = bid; lb < 768; lb += NB) {
        int bx = lb >> 2, by = lb & 3;
        int c2t = by * 4 + wv;
        int n0 = bx * 16;
        f32x4 acc = {0.f, 0.f, 0.f, 0.f};
        const float* ap0 = wp + (size_t)(c2t * 16 + r16) * 288 + q * 8;
        const float* bp0 = B2 + ((size_t)q * 3072 + n0 + r16) * 8;
        #pragma unroll
        for (int ks = 0; ks < 9; ++ks) {
            float av[8], bv[8];
            *(float4*)av = *(const float4*)(ap0 + ks * 32);
            *(float4*)(av + 4) = *(const float4*)(ap0 + ks * 32 + 4);
            *(float4*)bv = *(const float4*)(bp0 + (size_t)ks * 98304);
            *(float4*)(bv + 4) = *(const float4*)(bp0 + (size_t)ks * 98304 + 4);
            bfrag ahi, alo, bhi, blo;
            split8(av, ahi, alo);
            split8(bv, bhi, blo);
            acc = __builtin_amdgcn_mfma_f32_16x16x32_bf16(ahi, bhi, acc, 0, 0, 0);
            acc = __builtin_amdgcn_mfma_f32_16x16x32_bf16(ahi, blo, acc, 0, 0, 0);
            acc = __builtin_amdgcn_mfma_f32_16x16x32_bf16(alo, bhi, acc, 0, 0, 0);
        }
        int n = n0 + r16;
        int b = n / 24, s = n % 24;
        float vals[4], n2[4];
        #pragma unroll
        for (int rr = 0; rr < 4; ++rr) {
            float xv = acc[rr] + bp[c2t * 16 + q * 4 + rr];
            vals[rr] = xv;
            n2[rr] = xv * xv;
        }
        #pragma unroll
        for (int rr = 0; rr < 4; ++rr) {
            n2[rr] += __shfl_xor(n2[rr], 1, 64);
            n2[rr] += __shfl_xor(n2[rr], 2, 64);
            n2[rr] += __shfl_xor(n2[rr], 4, 64);
        }
        #pragma unroll
        for (int rr = 0; rr < 4; ++rr) {
            int c2 = c2t * 16 + q * 4 + rr;
            int cap = c2 * 3 + (s >> 3);
            int d = s & 7;
            float nr = sqrtf(n2[rr]);
            u2[((size_t)(cap * 2 + (d >> 2)) * 128 + b) * 4 + (d & 3)]
                = vals[rr] * nr / (1.f + n2[rr]);
        }
    }
    gbar(cnt, 2);

    // ---- P3: stage W tile ONCE (persists for all 5 routing passes) + spass0
    int o = bid >> 3, it = bid & 7, i0 = it * 96;
    #pragma unroll
    for (int itr = 0; itr < 12; ++itr) {
        int F = tid + 256 * itr;      // 0..3071 float4s
        int cap = F >> 5, slot = F & 31;
        *(float4*)(smem + cap * WPITCH + slot * 4) =
            *(const float4*)(W + ((size_t)(i0 + cap) * 64 + o) * 128 + slot * 4);
    }
    __syncthreads();
    spass_phase<true>(smem, u2, nullptr, nullptr, nullptr, s_part, o, it, wv, q, r16);
    gbar(cnt, 3);

    // ---- P4: squash -> v_t (uniform c folded: 1/64)
    squashv_phase(s_part, v, 1.f / 64.f, true, bid * 256 + tid);
    gbar(cnt, 4);

    // ---- P5: bpass0 (blog =)
    bpass_phase<false>(smem, u2, v, blog, o, it, wv, l);
    gbar(cnt, 5);

    // ---- P6: mz
    for (int lb = bid; lb < 768; lb += NB)
        if (tid < 128) mz_phase(blog, m_, z_, lb, tid);
    gbar(cnt, 6);

    // ---- P7: spass1
    spass_phase<false>(smem, u2, blog, m_, z_, s_part, o, it, wv, q, r16);
    gbar(cnt, 7);

    // ---- P8: squash -> v_t
    squashv_phase(s_part, v, 1.f, true, bid * 256 + tid);
    gbar(cnt, 8);

    // ---- P9: bpass1 (blog +=)
    bpass_phase<true>(smem, u2, v, blog, o, it, wv, l);
    gbar(cnt, 9);

    // ---- P10: mz
    for (int lb = bid; lb < 768; lb += NB)
        if (tid < 128) mz_phase(blog, m_, z_, lb, tid);
    gbar(cnt, 10);

    // ---- P11: spass2
    spass_phase<false>(smem, u2, blog, m_, z_, s_part, o, it, wv, q, r16);
    gbar(cnt, 11);

    // ---- P12: final squash -> out[b][o][k]
    squashv_phase(s_part, out, 1.f, false, bid * 256 + tid);
}

extern "C" void kernel_launch(void* const* d_in, const int* in_sizes, int n_in,
                              void* d_out, int out_size, void* d_ws, size_t ws_size,
                              hipStream_t stream) {
    const float* x  = (const float*)d_in[0];
    const float* w1 = (const float*)d_in[1];
    const float* b1 = (const float*)d_in[2];
    const float* wp = (const float*)d_in[3];
    const float* bp = (const float*)d_in[4];
    const float* W  = (const float*)d_in[5];
    float* out = (float*)d_out;
    float* ws = (float*)d_ws;
    int* cnt = (int*)(ws + 8933376);   // 16 barrier slots after h1 region

    hipMemsetAsync(cnt, 0, 64, stream);
    caps_mega<<<NB, 256, 0, stream>>>(x, w1, b1, wp, bp, W, out, ws, cnt);
}

// Round 12
// 174.761 us; speedup vs baseline: 9.0655x; 9.0655x over previous
//
#include <hip/hip_runtime.h>
#include <math.h>

typedef __attribute__((ext_vector_type(8))) short bfrag;    // 8 bf16 = 4 VGPR
typedef __attribute__((ext_vector_type(4))) float f32x4;    // 16x16 accumulator
typedef __attribute__((ext_vector_type(16))) float f32x16;  // 32x32 accumulator

// split 8 f32 into bf16 hi + lo; (hh+hl+lh) ~ fp32. trunc8: hi only (~2^-9 rel).
__device__ __forceinline__ void split8(const float* x, bfrag& hi, bfrag& lo) {
    #pragma unroll
    for (int j = 0; j < 8; ++j) {
        unsigned xb = __float_as_uint(x[j]);
        unsigned hb = xb & 0xffff0000u;
        float lf = x[j] - __uint_as_float(hb);
        hi[j] = (short)(xb >> 16);
        lo[j] = (short)(__float_as_uint(lf) >> 16);
    }
}
__device__ __forceinline__ void trunc8(const float* x, bfrag& hi) {
    #pragma unroll
    for (int j = 0; j < 8; ++j) hi[j] = (short)(__float_as_uint(x[j]) >> 16);
}

// ---------------- front: conv1 + im2col fused, one block per batch element.
// x(b,3,32,42) -> h1 in LDS (relu) -> B2[ko][n=(b,s)][8]
__global__ __launch_bounds__(256) void front_kernel(
    const float* __restrict__ x, const float* __restrict__ w1,
    const float* __restrict__ b1, float* __restrict__ B2) {
    __shared__ float xl[4032];
    __shared__ float wl[3456];
    __shared__ float hl[3744];
    int b = blockIdx.x, tid = threadIdx.x;
    const float* xb = x + (size_t)b * 4032;
    #pragma unroll
    for (int i = 0; i < 4; ++i) {
        int idx = tid + 256 * i;
        if (idx < 1008) *(float4*)(xl + idx * 4) = *(const float4*)(xb + idx * 4);
        if (idx < 864)  *(float4*)(wl + idx * 4) = *(const float4*)(w1 + idx * 4);
    }
    __syncthreads();
    for (int idx = tid; idx < 3744; idx += 256) {
        int oc = idx / 117, r = idx % 117;
        int oh = r / 13, ow = r % 13;
        float acc = b1[oc];
        #pragma unroll
        for (int ic = 0; ic < 3; ++ic) {
            const float* xc = xl + ic * 1344 + (oh * 3) * 42 + ow * 3;
            const float* wc = wl + (oc * 3 + ic) * 36;
            #pragma unroll
            for (int kh = 0; kh < 6; ++kh)
                #pragma unroll
                for (int kw = 0; kw < 6; ++kw)
                    acc += xc[kh * 42 + kw] * wc[kh * 6 + kw];
        }
        hl[idx] = fmaxf(acc, 0.f);
    }
    __syncthreads();
    for (int f = tid; f < 864; f += 256) {     // (ko, s)
        int ko = f / 24, s = f % 24;
        int h = s / 6, w = s % 6;
        float o8[8];
        #pragma unroll
        for (int j = 0; j < 8; ++j) {
            int k = ko * 8 + j;
            int ic = k / 9, rr = k % 9;
            int kh = rr / 3, kw = rr % 3;
            o8[j] = hl[ic * 117 + (2 * h + kh) * 13 + (2 * w + kw)];
        }
        float* dst = B2 + ((size_t)ko * 3072 + b * 24 + s) * 8;
        *(float4*)dst = *(const float4*)o8;
        *(float4*)(dst + 4) = *(const float4*)(o8 + 4);
    }
}

// ---------------- pc GEMM (MFMA) + bias + squash -> u2[i][dh][b][4]
__global__ __launch_bounds__(256) void pc_gemm_kernel(
    const float* __restrict__ wpc, const float* __restrict__ bias,
    const float* __restrict__ B2, float* __restrict__ u2) {
    int wv = threadIdx.x >> 6;
    int l = threadIdx.x & 63;
    int q = l >> 4, r16 = l & 15;
    int c2t = blockIdx.y * 4 + wv;
    int n0 = blockIdx.x * 16;
    f32x4 acc = {0.f, 0.f, 0.f, 0.f};
    const float* ap0 = wpc + (size_t)(c2t * 16 + r16) * 288 + q * 8;
    const float* bp0 = B2 + ((size_t)q * 3072 + n0 + r16) * 8;
    #pragma unroll
    for (int ks = 0; ks < 9; ++ks) {
        float av[8], bv[8];
        *(float4*)av = *(const float4*)(ap0 + ks * 32);
        *(float4*)(av + 4) = *(const float4*)(ap0 + ks * 32 + 4);
        *(float4*)bv = *(const float4*)(bp0 + (size_t)ks * 98304);
        *(float4*)(bv + 4) = *(const float4*)(bp0 + (size_t)ks * 98304 + 4);
        bfrag ahi, alo, bhi, blo;
        split8(av, ahi, alo);
        split8(bv, bhi, blo);
        acc = __builtin_amdgcn_mfma_f32_16x16x32_bf16(ahi, bhi, acc, 0, 0, 0);
        acc = __builtin_amdgcn_mfma_f32_16x16x32_bf16(ahi, blo, acc, 0, 0, 0);
        acc = __builtin_amdgcn_mfma_f32_16x16x32_bf16(alo, bhi, acc, 0, 0, 0);
    }
    int n = n0 + r16;
    int b = n / 24, s = n % 24;
    float vals[4], n2[4];
    #pragma unroll
    for (int r = 0; r < 4; ++r) {
        float xv = acc[r] + bias[c2t * 16 + q * 4 + r];
        vals[r] = xv;
        n2[r] = xv * xv;
    }
    #pragma unroll
    for (int r = 0; r < 4; ++r) {
        n2[r] += __shfl_xor(n2[r], 1, 64);
        n2[r] += __shfl_xor(n2[r], 2, 64);
        n2[r] += __shfl_xor(n2[r], 4, 64);
    }
    #pragma unroll
    for (int r = 0; r < 4; ++r) {
        int c2 = c2t * 16 + q * 4 + r;
        int cap = c2 * 3 + (s >> 3);
        int d = s & 7;
        float nr = sqrtf(n2[r]);
        u2[((size_t)(cap * 2 + (d >> 2)) * 128 + b) * 4 + (d & 3)]
            = vals[r] * nr / (1.f + n2[r]);
    }
}

// ---------------- s-pass: W staged in LDS; u/blog pipelined 3-deep.
// c = exp(blog)/zsum (no max subtraction — |blog| bounded ~40, exp fits f32).
// 2-term MFMA: W split (hi+lo), c*u truncated -> ~2^-9 rel on s (then v normalized).
template <bool UNIFORM>
__global__ __launch_bounds__(256, 4) void spass_kernel(
    const float* __restrict__ W, const float* __restrict__ u2,
    const float* __restrict__ blog, const float* __restrict__ zsum,
    float* __restrict__ s_part) {
    int o = blockIdx.x;
    int it = blockIdx.y;       // 0..23 (32 caps)
    int tid = threadIdx.x;
    int wv = tid >> 6;
    int l = tid & 63;
    int q = l >> 4, r16 = l & 15;
    int i0 = it * 32;
    __shared__ float wl[32 * 132];

    float4 ua[3][2][2];
    float blv[3][2], zv[3][2];
    auto issue = [&](int s, int buf) {
        int cap = i0 + s * 4 + q;
        #pragma unroll
        for (int m = 0; m < 2; ++m) {
            int b = wv * 32 + m * 16 + r16;
            ua[buf][m][0] = *(const float4*)(u2 + ((size_t)(cap * 2 + 0) * 128 + b) * 4);
            ua[buf][m][1] = *(const float4*)(u2 + ((size_t)(cap * 2 + 1) * 128 + b) * 4);
            if (!UNIFORM) {
                blv[buf][m] = blog[((size_t)o * 768 + cap) * 128 + b];
                zv[buf][m]  = zsum[cap * 128 + b];
            }
        }
    };

    issue(0, 0);
    issue(1, 1);
    #pragma unroll
    for (int itr = 0; itr < 4; ++itr) {
        int F = tid + 256 * itr;
        int cap = F >> 5, slot = F & 31;
        *(float4*)(wl + cap * 132 + slot * 4) =
            *(const float4*)(W + ((size_t)(i0 + cap) * 64 + o) * 128 + slot * 4);
    }
    __syncthreads();

    f32x4 acc0 = {0.f, 0.f, 0.f, 0.f};
    f32x4 acc1 = {0.f, 0.f, 0.f, 0.f};
    #pragma unroll
    for (int s = 0; s < 8; ++s) {
        int cur = s % 3;
        if (s < 6) issue(s + 2, (s + 2) % 3);
        const float* wp = wl + (s * 4 + q) * 132 + r16 * 8;
        float wv8[8];
        *(float4*)(wv8) = *(const float4*)wp;
        *(float4*)(wv8 + 4) = *(const float4*)(wp + 4);
        bfrag bhi, blo;
        split8(wv8, bhi, blo);
        #pragma unroll
        for (int m = 0; m < 2; ++m) {
            float uv[8];
            *(float4*)(uv) = ua[cur][m][0];
            *(float4*)(uv + 4) = ua[cur][m][1];
            if (!UNIFORM) {
                float c = __expf(blv[cur][m]) / zv[cur][m];
                #pragma unroll
                for (int j = 0; j < 8; ++j) uv[j] *= c;
            }
            bfrag ahi;
            trunc8(uv, ahi);
            if (m == 0) {
                acc0 = __builtin_amdgcn_mfma_f32_16x16x32_bf16(ahi, bhi, acc0, 0, 0, 0);
                acc0 = __builtin_amdgcn_mfma_f32_16x16x32_bf16(ahi, blo, acc0, 0, 0, 0);
            } else {
                acc1 = __builtin_amdgcn_mfma_f32_16x16x32_bf16(ahi, bhi, acc1, 0, 0, 0);
                acc1 = __builtin_amdgcn_mfma_f32_16x16x32_bf16(ahi, blo, acc1, 0, 0, 0);
            }
        }
    }
    #pragma unroll
    for (int reg = 0; reg < 4; ++reg) {
        int b0 = wv * 32 + q * 4 + reg;
        s_part[(((size_t)it * 128 + b0) * 64 + o) * 16 + r16] = acc0[reg];
        s_part[(((size_t)it * 128 + b0 + 16) * 64 + o) * 16 + r16] = acc1[reg];
    }
}

// ---------------- reduce partials + squash -> v ([b][o][k] or [o][b][k])
template <bool TRANSPOSED>
__global__ __launch_bounds__(256) void squashv_kernel(
    const float* __restrict__ s_part, float* __restrict__ v, float scale) {
    int idx = blockIdx.x * 256 + threadIdx.x;
    float acc = 0.f;
    #pragma unroll
    for (int it = 0; it < 24; ++it) acc += s_part[(size_t)it * 131072 + idx];
    acc *= scale;
    float n2 = acc * acc;
    n2 += __shfl_xor(n2, 1, 64);
    n2 += __shfl_xor(n2, 2, 64);
    n2 += __shfl_xor(n2, 4, 64);
    n2 += __shfl_xor(n2, 8, 64);
    float n = sqrtf(n2);
    float val = acc * n / (1.f + n2);
    if (TRANSPOSED) {
        int k = idx & 15, o = (idx >> 4) & 63, b = idx >> 10;
        v[((size_t)o * 128 + b) * 16 + k] = val;
    } else {
        v[idx] = val;
    }
}

// ---------------- b-pass: blog (+)= sum_d u*(W x v); also zsum[i,b] += exp(blog_new)
template <bool ACCUM>
__global__ __launch_bounds__(256, 4) void bpass_kernel(
    const float* __restrict__ W, const float* __restrict__ u2,
    const float* __restrict__ v_t, float* __restrict__ blog,
    float* __restrict__ zsum) {
    int o = blockIdx.x, it = blockIdx.y;   // it: 0..23 (32 caps)
    int tid = threadIdx.x;
    int wv = tid >> 6;
    int l = tid & 63;
    int r = l & 31;
    int kh = l >> 5;
    int capB = it * 32;
    __shared__ float wl[32 * 164];
    #pragma unroll
    for (int itr = 0; itr < 4; ++itr) {
        int F = tid + 256 * itr;
        int cap = F >> 5, slot = F & 31;
        int k = slot >> 1, dh = slot & 1;
        float4 t4 = *(const float4*)(W + ((size_t)(capB + cap) * 64 + o) * 128 + k * 8 + dh * 4);
        float* dst = wl + cap * 164 + (dh * 4) * 20 + k;
        dst[0] = t4.x; dst[20] = t4.y; dst[40] = t4.z; dst[60] = t4.w;
    }
    bfrag vhi[4], vlo[4];
    #pragma unroll
    for (int nt = 0; nt < 4; ++nt) {
        const float* vp = v_t + ((size_t)o * 128 + nt * 32 + r) * 16 + kh * 8;
        float vv8[8];
        *(float4*)(vv8) = *(const float4*)vp;
        *(float4*)(vv8 + 4) = *(const float4*)(vp + 4);
        split8(vv8, vhi[nt], vlo[nt]);
    }
    __syncthreads();
    #pragma unroll
    for (int mt = 0; mt < 2; ++mt) {
        int cl = wv * 8 + mt * 4 + (r >> 3);
        const float* ap = wl + cl * 164 + (r & 7) * 20 + kh * 8;
        float a8[8];
        *(float4*)(a8) = *(const float4*)ap;
        *(float4*)(a8 + 4) = *(const float4*)(ap + 4);
        int capg = capB + wv * 8 + mt * 4;
        int gw = kh * 2;
        float prevv[4][2];
        if (ACCUM) {
            #pragma unroll
            for (int nt = 0; nt < 4; ++nt) {
                int b = nt * 32 + r;
                #pragma unroll
                for (int gg = 0; gg < 2; ++gg)
                    prevv[nt][gg] = blog[((size_t)o * 768 + capg + gw + gg) * 128 + b];
            }
        }
        float4 u4b[2][4];
        #pragma unroll
        for (int g = 0; g < 4; ++g)
            u4b[0][g] = *(const float4*)(u2 + ((size_t)((capg + g) * 2 + kh) * 128 + r) * 4);
        bfrag ahi, alo;
        split8(a8, ahi, alo);
        #pragma unroll
        for (int nt = 0; nt < 4; ++nt) {
            int cur = nt & 1;
            if (nt < 3) {
                int bn = (nt + 1) * 32 + r;
                #pragma unroll
                for (int g = 0; g < 4; ++g)
                    u4b[cur ^ 1][g] = *(const float4*)(u2 + ((size_t)((capg + g) * 2 + kh) * 128 + bn) * 4);
            }
            int b = nt * 32 + r;
            f32x16 acc;
            #pragma unroll
            for (int z = 0; z < 16; ++z) acc[z] = 0.f;
            acc = __builtin_amdgcn_mfma_f32_32x32x16_bf16(ahi, vhi[nt], acc, 0, 0, 0);
            acc = __builtin_amdgcn_mfma_f32_32x32x16_bf16(ahi, vlo[nt], acc, 0, 0, 0);
            acc = __builtin_amdgcn_mfma_f32_32x32x16_bf16(alo, vhi[nt], acc, 0, 0, 0);
            float full[4];
            #pragma unroll
            for (int g = 0; g < 4; ++g) {
                float part = u4b[cur][g].x * acc[g * 4 + 0] + u4b[cur][g].y * acc[g * 4 + 1]
                           + u4b[cur][g].z * acc[g * 4 + 2] + u4b[cur][g].w * acc[g * 4 + 3];
                full[g] = part + __shfl_xor(part, 32, 64);
            }
            #pragma unroll
            for (int gg = 0; gg < 2; ++gg) {
                int g = gw + gg;
                int cap = capg + g;
                float nb = (ACCUM ? prevv[nt][gg] : 0.f) + full[g];
                blog[((size_t)o * 768 + cap) * 128 + b] = nb;
                atomicAdd(zsum + cap * 128 + b, __expf(nb));
            }
        }
    }
}

extern "C" void kernel_launch(void* const* d_in, const int* in_sizes, int n_in,
                              void* d_out, int out_size, void* d_ws, size_t ws_size,
                              hipStream_t stream) {
    const float* x  = (const float*)d_in[0];
    const float* w1 = (const float*)d_in[1];
    const float* b1 = (const float*)d_in[2];
    const float* wp = (const float*)d_in[3];
    const float* bp = (const float*)d_in[4];
    const float* W  = (const float*)d_in[5];
    float* out = (float*)d_out;
    float* ws = (float*)d_ws;

    float* u2     = ws;                  // 786432
    float* blog   = ws + 786432;         // 6291456
    float* zsum   = ws + 7077888;        // 98304
    float* v      = ws + 7274496;        // 131072
    float* s_part = ws + 7405568;        // 24 * 131072
    float* B2     = s_part;              // 884736, dead before spass writes s_part

    front_kernel<<<128, 256, 0, stream>>>(x, w1, b1, B2);
    pc_gemm_kernel<<<dim3(192, 4), 256, 0, stream>>>(wp, bp, B2, u2);

    // iteration 0: c uniform (1/64 folded into squash scale)
    spass_kernel<true><<<dim3(64, 24), 256, 0, stream>>>(W, u2, nullptr, nullptr, s_part);
    squashv_kernel<true><<<512, 256, 0, stream>>>(s_part, v, 1.f / 64.f);
    hipMemsetAsync(zsum, 0, 98304 * sizeof(float), stream);
    bpass_kernel<false><<<dim3(64, 24), 256, 0, stream>>>(W, u2, v, blog, zsum);

    // iteration 1 (softmax denominator from bpass atomics; no max needed)
    spass_kernel<false><<<dim3(64, 24), 256, 0, stream>>>(W, u2, blog, zsum, s_part);
    squashv_kernel<true><<<512, 256, 0, stream>>>(s_part, v, 1.f);
    hipMemsetAsync(zsum, 0, 98304 * sizeof(float), stream);
    bpass_kernel<true><<<dim3(64, 24), 256, 0, stream>>>(W, u2, v, blog, zsum);

    // final
    spass_kernel<false><<<dim3(64, 24), 256, 0, stream>>>(W, u2, blog, zsum, s_part);
    squashv_kernel<false><<<512, 256, 0, stream>>>(s_part, out, 1.f);
}

// Round 13
// 171.829 us; speedup vs baseline: 9.2202x; 1.0171x over previous
//
#include <hip/hip_runtime.h>
#include <math.h>

typedef __attribute__((ext_vector_type(8))) short bfrag;    // 8 bf16 = 4 VGPR
typedef __attribute__((ext_vector_type(4))) float f32x4;    // 16x16 accumulator
typedef __attribute__((ext_vector_type(16))) float f32x16;  // 32x32 accumulator

// split 8 f32 into bf16 hi + lo; (hh+hl+lh) ~ fp32. trunc8: hi only (~2^-9 rel).
__device__ __forceinline__ void split8(const float* x, bfrag& hi, bfrag& lo) {
    #pragma unroll
    for (int j = 0; j < 8; ++j) {
        unsigned xb = __float_as_uint(x[j]);
        unsigned hb = xb & 0xffff0000u;
        float lf = x[j] - __uint_as_float(hb);
        hi[j] = (short)(xb >> 16);
        lo[j] = (short)(__float_as_uint(lf) >> 16);
    }
}
__device__ __forceinline__ void trunc8(const float* x, bfrag& hi) {
    #pragma unroll
    for (int j = 0; j < 8; ++j) hi[j] = (short)(__float_as_uint(x[j]) >> 16);
}

// ---------------- front: conv1 + im2col fused, one block per batch element.
__global__ __launch_bounds__(256) void front_kernel(
    const float* __restrict__ x, const float* __restrict__ w1,
    const float* __restrict__ b1, float* __restrict__ B2) {
    __shared__ float xl[4032];
    __shared__ float wl[3456];
    __shared__ float hl[3744];
    int b = blockIdx.x, tid = threadIdx.x;
    const float* xb = x + (size_t)b * 4032;
    #pragma unroll
    for (int i = 0; i < 4; ++i) {
        int idx = tid + 256 * i;
        if (idx < 1008) *(float4*)(xl + idx * 4) = *(const float4*)(xb + idx * 4);
        if (idx < 864)  *(float4*)(wl + idx * 4) = *(const float4*)(w1 + idx * 4);
    }
    __syncthreads();
    for (int idx = tid; idx < 3744; idx += 256) {
        int oc = idx / 117, r = idx % 117;
        int oh = r / 13, ow = r % 13;
        float acc = b1[oc];
        #pragma unroll
        for (int ic = 0; ic < 3; ++ic) {
            const float* xc = xl + ic * 1344 + (oh * 3) * 42 + ow * 3;
            const float* wc = wl + (oc * 3 + ic) * 36;
            #pragma unroll
            for (int kh = 0; kh < 6; ++kh)
                #pragma unroll
                for (int kw = 0; kw < 6; ++kw)
                    acc += xc[kh * 42 + kw] * wc[kh * 6 + kw];
        }
        hl[idx] = fmaxf(acc, 0.f);
    }
    __syncthreads();
    for (int f = tid; f < 864; f += 256) {     // (ko, s)
        int ko = f / 24, s = f % 24;
        int h = s / 6, w = s % 6;
        float o8[8];
        #pragma unroll
        for (int j = 0; j < 8; ++j) {
            int k = ko * 8 + j;
            int ic = k / 9, rr = k % 9;
            int kh = rr / 3, kw = rr % 3;
            o8[j] = hl[ic * 117 + (2 * h + kh) * 13 + (2 * w + kw)];
        }
        float* dst = B2 + ((size_t)ko * 3072 + b * 24 + s) * 8;
        *(float4*)dst = *(const float4*)o8;
        *(float4*)(dst + 4) = *(const float4*)(o8 + 4);
    }
}

// ---------------- pc GEMM (MFMA) + bias + squash -> u2[i][dh][b][4]
__global__ __launch_bounds__(256) void pc_gemm_kernel(
    const float* __restrict__ wpc, const float* __restrict__ bias,
    const float* __restrict__ B2, float* __restrict__ u2) {
    int wv = threadIdx.x >> 6;
    int l = threadIdx.x & 63;
    int q = l >> 4, r16 = l & 15;
    int c2t = blockIdx.y * 4 + wv;
    int n0 = blockIdx.x * 16;
    f32x4 acc = {0.f, 0.f, 0.f, 0.f};
    const float* ap0 = wpc + (size_t)(c2t * 16 + r16) * 288 + q * 8;
    const float* bp0 = B2 + ((size_t)q * 3072 + n0 + r16) * 8;
    #pragma unroll
    for (int ks = 0; ks < 9; ++ks) {
        float av[8], bv[8];
        *(float4*)av = *(const float4*)(ap0 + ks * 32);
        *(float4*)(av + 4) = *(const float4*)(ap0 + ks * 32 + 4);
        *(float4*)bv = *(const float4*)(bp0 + (size_t)ks * 98304);
        *(float4*)(bv + 4) = *(const float4*)(bp0 + (size_t)ks * 98304 + 4);
        bfrag ahi, alo, bhi, blo;
        split8(av, ahi, alo);
        split8(bv, bhi, blo);
        acc = __builtin_amdgcn_mfma_f32_16x16x32_bf16(ahi, bhi, acc, 0, 0, 0);
        acc = __builtin_amdgcn_mfma_f32_16x16x32_bf16(ahi, blo, acc, 0, 0, 0);
        acc = __builtin_amdgcn_mfma_f32_16x16x32_bf16(alo, bhi, acc, 0, 0, 0);
    }
    int n = n0 + r16;
    int b = n / 24, s = n % 24;
    float vals[4], n2[4];
    #pragma unroll
    for (int r = 0; r < 4; ++r) {
        float xv = acc[r] + bias[c2t * 16 + q * 4 + r];
        vals[r] = xv;
        n2[r] = xv * xv;
    }
    #pragma unroll
    for (int r = 0; r < 4; ++r) {
        n2[r] += __shfl_xor(n2[r], 1, 64);
        n2[r] += __shfl_xor(n2[r], 2, 64);
        n2[r] += __shfl_xor(n2[r], 4, 64);
    }
    #pragma unroll
    for (int r = 0; r < 4; ++r) {
        int c2 = c2t * 16 + q * 4 + r;
        int cap = c2 * 3 + (s >> 3);
        int d = s & 7;
        float nr = sqrtf(n2[r]);
        u2[((size_t)(cap * 2 + (d >> 2)) * 128 + b) * 4 + (d & 3)]
            = vals[r] * nr / (1.f + n2[r]);
    }
}

// ---------------- s-pass: W staged in LDS; u/blog pipelined 3-deep.
// c = exp(blog)/zsum (no max subtraction — |blog| bounded, exp fits f32).
template <bool UNIFORM>
__global__ __launch_bounds__(256, 4) void spass_kernel(
    const float* __restrict__ W, const float* __restrict__ u2,
    const float* __restrict__ blog, const float* __restrict__ zsum,
    float* __restrict__ s_part) {
    int o = blockIdx.x;
    int it = blockIdx.y;       // 0..23 (32 caps)
    int tid = threadIdx.x;
    int wv = tid >> 6;
    int l = tid & 63;
    int q = l >> 4, r16 = l & 15;
    int i0 = it * 32;
    __shared__ float wl[32 * 132];

    float4 ua[3][2][2];
    float blv[3][2], zv[3][2];
    auto issue = [&](int s, int buf) {
        int cap = i0 + s * 4 + q;
        #pragma unroll
        for (int m = 0; m < 2; ++m) {
            int b = wv * 32 + m * 16 + r16;
            ua[buf][m][0] = *(const float4*)(u2 + ((size_t)(cap * 2 + 0) * 128 + b) * 4);
            ua[buf][m][1] = *(const float4*)(u2 + ((size_t)(cap * 2 + 1) * 128 + b) * 4);
            if (!UNIFORM) {
                blv[buf][m] = blog[((size_t)o * 768 + cap) * 128 + b];
                zv[buf][m]  = zsum[cap * 128 + b];
            }
        }
    };

    issue(0, 0);
    issue(1, 1);
    #pragma unroll
    for (int itr = 0; itr < 4; ++itr) {
        int F = tid + 256 * itr;
        int cap = F >> 5, slot = F & 31;
        *(float4*)(wl + cap * 132 + slot * 4) =
            *(const float4*)(W + ((size_t)(i0 + cap) * 64 + o) * 128 + slot * 4);
    }
    __syncthreads();

    f32x4 acc0 = {0.f, 0.f, 0.f, 0.f};
    f32x4 acc1 = {0.f, 0.f, 0.f, 0.f};
    #pragma unroll
    for (int s = 0; s < 8; ++s) {
        int cur = s % 3;
        if (s < 6) issue(s + 2, (s + 2) % 3);
        const float* wp = wl + (s * 4 + q) * 132 + r16 * 8;
        float wv8[8];
        *(float4*)(wv8) = *(const float4*)wp;
        *(float4*)(wv8 + 4) = *(const float4*)(wp + 4);
        bfrag bhi, blo;
        split8(wv8, bhi, blo);
        #pragma unroll
        for (int m = 0; m < 2; ++m) {
            float uv[8];
            *(float4*)(uv) = ua[cur][m][0];
            *(float4*)(uv + 4) = ua[cur][m][1];
            if (!UNIFORM) {
                float c = __expf(blv[cur][m]) / zv[cur][m];
                #pragma unroll
                for (int j = 0; j < 8; ++j) uv[j] *= c;
            }
            bfrag ahi;
            trunc8(uv, ahi);
            if (m == 0) {
                acc0 = __builtin_amdgcn_mfma_f32_16x16x32_bf16(ahi, bhi, acc0, 0, 0, 0);
                acc0 = __builtin_amdgcn_mfma_f32_16x16x32_bf16(ahi, blo, acc0, 0, 0, 0);
            } else {
                acc1 = __builtin_amdgcn_mfma_f32_16x16x32_bf16(ahi, bhi, acc1, 0, 0, 0);
                acc1 = __builtin_amdgcn_mfma_f32_16x16x32_bf16(ahi, blo, acc1, 0, 0, 0);
            }
        }
    }
    #pragma unroll
    for (int reg = 0; reg < 4; ++reg) {
        int b0 = wv * 32 + q * 4 + reg;
        s_part[(((size_t)it * 128 + b0) * 64 + o) * 16 + r16] = acc0[reg];
        s_part[(((size_t)it * 128 + b0 + 16) * 64 + o) * 16 + r16] = acc1[reg];
    }
}

// ---------------- reduce partials + squash -> v; optionally zero zsum for next bpass
// (replaces hipMemsetAsync: the runtime's 384KB fill kernel measured 42 us!)
template <bool TRANSPOSED>
__global__ __launch_bounds__(256) void squashv_kernel(
    const float* __restrict__ s_part, float* __restrict__ v, float scale,
    float* __restrict__ zsum_zero) {
    int idx = blockIdx.x * 256 + threadIdx.x;
    if (zsum_zero && idx < 98304) zsum_zero[idx] = 0.f;
    float acc = 0.f;
    #pragma unroll
    for (int it = 0; it < 24; ++it) acc += s_part[(size_t)it * 131072 + idx];
    acc *= scale;
    float n2 = acc * acc;
    n2 += __shfl_xor(n2, 1, 64);
    n2 += __shfl_xor(n2, 2, 64);
    n2 += __shfl_xor(n2, 4, 64);
    n2 += __shfl_xor(n2, 8, 64);
    float n = sqrtf(n2);
    float val = acc * n / (1.f + n2);
    if (TRANSPOSED) {
        int k = idx & 15, o = (idx >> 4) & 63, b = idx >> 10;
        v[((size_t)o * 128 + b) * 16 + k] = val;
    } else {
        v[idx] = val;
    }
}

// ---------------- b-pass: blog (+)= sum_d u*(W x v); also zsum[i,b] += exp(blog_new)
template <bool ACCUM>
__global__ __launch_bounds__(256, 4) void bpass_kernel(
    const float* __restrict__ W, const float* __restrict__ u2,
    const float* __restrict__ v_t, float* __restrict__ blog,
    float* __restrict__ zsum) {
    int o = blockIdx.x, it = blockIdx.y;   // it: 0..23 (32 caps)
    int tid = threadIdx.x;
    int wv = tid >> 6;
    int l = tid & 63;
    int r = l & 31;
    int kh = l >> 5;
    int capB = it * 32;
    __shared__ float wl[32 * 164];
    #pragma unroll
    for (int itr = 0; itr < 4; ++itr) {
        int F = tid + 256 * itr;
        int cap = F >> 5, slot = F & 31;
        int k = slot >> 1, dh = slot & 1;
        float4 t4 = *(const float4*)(W + ((size_t)(capB + cap) * 64 + o) * 128 + k * 8 + dh * 4);
        float* dst = wl + cap * 164 + (dh * 4) * 20 + k;
        dst[0] = t4.x; dst[20] = t4.y; dst[40] = t4.z; dst[60] = t4.w;
    }
    bfrag vhi[4], vlo[4];
    #pragma unroll
    for (int nt = 0; nt < 4; ++nt) {
        const float* vp = v_t + ((size_t)o * 128 + nt * 32 + r) * 16 + kh * 8;
        float vv8[8];
        *(float4*)(vv8) = *(const float4*)vp;
        *(float4*)(vv8 + 4) = *(const float4*)(vp + 4);
        split8(vv8, vhi[nt], vlo[nt]);
    }
    __syncthreads();
    #pragma unroll
    for (int mt = 0; mt < 2; ++mt) {
        int cl = wv * 8 + mt * 4 + (r >> 3);
        const float* ap = wl + cl * 164 + (r & 7) * 20 + kh * 8;
        float a8[8];
        *(float4*)(a8) = *(const float4*)ap;
        *(float4*)(a8 + 4) = *(const float4*)(ap + 4);
        int capg = capB + wv * 8 + mt * 4;
        int gw = kh * 2;
        float prevv[4][2];
        if (ACCUM) {
            #pragma unroll
            for (int nt = 0; nt < 4; ++nt) {
                int b = nt * 32 + r;
                #pragma unroll
                for (int gg = 0; gg < 2; ++gg)
                    prevv[nt][gg] = blog[((size_t)o * 768 + capg + gw + gg) * 128 + b];
            }
        }
        float4 u4b[2][4];
        #pragma unroll
        for (int g = 0; g < 4; ++g)
            u4b[0][g] = *(const float4*)(u2 + ((size_t)((capg + g) * 2 + kh) * 128 + r) * 4);
        bfrag ahi, alo;
        split8(a8, ahi, alo);
        #pragma unroll
        for (int nt = 0; nt < 4; ++nt) {
            int cur = nt & 1;
            if (nt < 3) {
                int bn = (nt + 1) * 32 + r;
                #pragma unroll
                for (int g = 0; g < 4; ++g)
                    u4b[cur ^ 1][g] = *(const float4*)(u2 + ((size_t)((capg + g) * 2 + kh) * 128 + bn) * 4);
            }
            int b = nt * 32 + r;
            f32x16 acc;
            #pragma unroll
            for (int z = 0; z < 16; ++z) acc[z] = 0.f;
            acc = __builtin_amdgcn_mfma_f32_32x32x16_bf16(ahi, vhi[nt], acc, 0, 0, 0);
            acc = __builtin_amdgcn_mfma_f32_32x32x16_bf16(ahi, vlo[nt], acc, 0, 0, 0);
            acc = __builtin_amdgcn_mfma_f32_32x32x16_bf16(alo, vhi[nt], acc, 0, 0, 0);
            float full[4];
            #pragma unroll
            for (int g = 0; g < 4; ++g) {
                float part = u4b[cur][g].x * acc[g * 4 + 0] + u4b[cur][g].y * acc[g * 4 + 1]
                           + u4b[cur][g].z * acc[g * 4 + 2] + u4b[cur][g].w * acc[g * 4 + 3];
                full[g] = part + __shfl_xor(part, 32, 64);
            }
            #pragma unroll
            for (int gg = 0; gg < 2; ++gg) {
                int g = gw + gg;
                int cap = capg + g;
                float nb = (ACCUM ? prevv[nt][gg] : 0.f) + full[g];
                blog[((size_t)o * 768 + cap) * 128 + b] = nb;
                atomicAdd(zsum + cap * 128 + b, __expf(nb));
            }
        }
    }
}

extern "C" void kernel_launch(void* const* d_in, const int* in_sizes, int n_in,
                              void* d_out, int out_size, void* d_ws, size_t ws_size,
                              hipStream_t stream) {
    const float* x  = (const float*)d_in[0];
    const float* w1 = (const float*)d_in[1];
    const float* b1 = (const float*)d_in[2];
    const float* wp = (const float*)d_in[3];
    const float* bp = (const float*)d_in[4];
    const float* W  = (const float*)d_in[5];
    float* out = (float*)d_out;
    float* ws = (float*)d_ws;

    float* u2     = ws;                  // 786432
    float* blog   = ws + 786432;         // 6291456
    float* zsum   = ws + 7077888;        // 98304
    float* v      = ws + 7274496;        // 131072
    float* s_part = ws + 7405568;        // 24 * 131072
    float* B2     = s_part;              // 884736, dead before spass writes s_part

    front_kernel<<<128, 256, 0, stream>>>(x, w1, b1, B2);
    pc_gemm_kernel<<<dim3(192, 4), 256, 0, stream>>>(wp, bp, B2, u2);

    // iteration 0: c uniform (1/64 folded into squash scale)
    spass_kernel<true><<<dim3(64, 24), 256, 0, stream>>>(W, u2, nullptr, nullptr, s_part);
    squashv_kernel<true><<<512, 256, 0, stream>>>(s_part, v, 1.f / 64.f, zsum);
    bpass_kernel<false><<<dim3(64, 24), 256, 0, stream>>>(W, u2, v, blog, zsum);

    // iteration 1 (softmax denominator from bpass atomics; no max needed)
    spass_kernel<false><<<dim3(64, 24), 256, 0, stream>>>(W, u2, blog, zsum, s_part);
    squashv_kernel<true><<<512, 256, 0, stream>>>(s_part, v, 1.f, zsum);
    bpass_kernel<true><<<dim3(64, 24), 256, 0, stream>>>(W, u2, v, blog, zsum);

    // final
    spass_kernel<false><<<dim3(64, 24), 256, 0, stream>>>(W, u2, blog, zsum, s_part);
    squashv_kernel<false><<<512, 256, 0, stream>>>(s_part, out, 1.f, nullptr);
}

// Round 14
// 144.849 us; speedup vs baseline: 10.9376x; 1.1863x over previous
//
#include <hip/hip_runtime.h>
#include <math.h>

typedef __attribute__((ext_vector_type(8))) short bfrag;    // 8 bf16 = 4 VGPR
typedef __attribute__((ext_vector_type(4))) float f32x4;    // 16x16 accumulator
typedef __attribute__((ext_vector_type(16))) float f32x16;  // 32x32 accumulator

// split 8 f32 into bf16 hi + lo; (hh+hl+lh) ~ fp32. trunc8: hi only (~2^-9 rel).
__device__ __forceinline__ void split8(const float* x, bfrag& hi, bfrag& lo) {
    #pragma unroll
    for (int j = 0; j < 8; ++j) {
        unsigned xb = __float_as_uint(x[j]);
        unsigned hb = xb & 0xffff0000u;
        float lf = x[j] - __uint_as_float(hb);
        hi[j] = (short)(xb >> 16);
        lo[j] = (short)(__float_as_uint(lf) >> 16);
    }
}
__device__ __forceinline__ void trunc8(const float* x, bfrag& hi) {
    #pragma unroll
    for (int j = 0; j < 8; ++j) hi[j] = (short)(__float_as_uint(x[j]) >> 16);
}

// ---------------- front: conv1 + im2col fused, one block per batch element.
__global__ __launch_bounds__(256) void front_kernel(
    const float* __restrict__ x, const float* __restrict__ w1,
    const float* __restrict__ b1, float* __restrict__ B2) {
    __shared__ float xl[4032];
    __shared__ float wl[3456];
    __shared__ float hl[3744];
    int b = blockIdx.x, tid = threadIdx.x;
    const float* xb = x + (size_t)b * 4032;
    #pragma unroll
    for (int i = 0; i < 4; ++i) {
        int idx = tid + 256 * i;
        if (idx < 1008) *(float4*)(xl + idx * 4) = *(const float4*)(xb + idx * 4);
        if (idx < 864)  *(float4*)(wl + idx * 4) = *(const float4*)(w1 + idx * 4);
    }
    __syncthreads();
    for (int idx = tid; idx < 3744; idx += 256) {
        int oc = idx / 117, r = idx % 117;
        int oh = r / 13, ow = r % 13;
        float acc = b1[oc];
        #pragma unroll
        for (int ic = 0; ic < 3; ++ic) {
            const float* xc = xl + ic * 1344 + (oh * 3) * 42 + ow * 3;
            const float* wc = wl + (oc * 3 + ic) * 36;
            #pragma unroll
            for (int kh = 0; kh < 6; ++kh)
                #pragma unroll
                for (int kw = 0; kw < 6; ++kw)
                    acc += xc[kh * 42 + kw] * wc[kh * 6 + kw];
        }
        hl[idx] = fmaxf(acc, 0.f);
    }
    __syncthreads();
    for (int f = tid; f < 864; f += 256) {     // (ko, s)
        int ko = f / 24, s = f % 24;
        int h = s / 6, w = s % 6;
        float o8[8];
        #pragma unroll
        for (int j = 0; j < 8; ++j) {
            int k = ko * 8 + j;
            int ic = k / 9, rr = k % 9;
            int kh = rr / 3, kw = rr % 3;
            o8[j] = hl[ic * 117 + (2 * h + kh) * 13 + (2 * w + kw)];
        }
        float* dst = B2 + ((size_t)ko * 3072 + b * 24 + s) * 8;
        *(float4*)dst = *(const float4*)o8;
        *(float4*)(dst + 4) = *(const float4*)(o8 + 4);
    }
}

// ---------------- pc GEMM (MFMA) + bias + squash -> u2[i][dh][b][4]
__global__ __launch_bounds__(256) void pc_gemm_kernel(
    const float* __restrict__ wpc, const float* __restrict__ bias,
    const float* __restrict__ B2, float* __restrict__ u2) {
    int wv = threadIdx.x >> 6;
    int l = threadIdx.x & 63;
    int q = l >> 4, r16 = l & 15;
    int c2t = blockIdx.y * 4 + wv;
    int n0 = blockIdx.x * 16;
    f32x4 acc = {0.f, 0.f, 0.f, 0.f};
    const float* ap0 = wpc + (size_t)(c2t * 16 + r16) * 288 + q * 8;
    const float* bp0 = B2 + ((size_t)q * 3072 + n0 + r16) * 8;
    #pragma unroll
    for (int ks = 0; ks < 9; ++ks) {
        float av[8], bv[8];
        *(float4*)av = *(const float4*)(ap0 + ks * 32);
        *(float4*)(av + 4) = *(const float4*)(ap0 + ks * 32 + 4);
        *(float4*)bv = *(const float4*)(bp0 + (size_t)ks * 98304);
        *(float4*)(bv + 4) = *(const float4*)(bp0 + (size_t)ks * 98304 + 4);
        bfrag ahi, alo, bhi, blo;
        split8(av, ahi, alo);
        split8(bv, bhi, blo);
        acc = __builtin_amdgcn_mfma_f32_16x16x32_bf16(ahi, bhi, acc, 0, 0, 0);
        acc = __builtin_amdgcn_mfma_f32_16x16x32_bf16(ahi, blo, acc, 0, 0, 0);
        acc = __builtin_amdgcn_mfma_f32_16x16x32_bf16(alo, bhi, acc, 0, 0, 0);
    }
    int n = n0 + r16;
    int b = n / 24, s = n % 24;
    float vals[4], n2[4];
    #pragma unroll
    for (int r = 0; r < 4; ++r) {
        float xv = acc[r] + bias[c2t * 16 + q * 4 + r];
        vals[r] = xv;
        n2[r] = xv * xv;
    }
    #pragma unroll
    for (int r = 0; r < 4; ++r) {
        n2[r] += __shfl_xor(n2[r], 1, 64);
        n2[r] += __shfl_xor(n2[r], 2, 64);
        n2[r] += __shfl_xor(n2[r], 4, 64);
    }
    #pragma unroll
    for (int r = 0; r < 4; ++r) {
        int c2 = c2t * 16 + q * 4 + r;
        int cap = c2 * 3 + (s >> 3);
        int d = s & 7;
        float nr = sqrtf(n2[r]);
        u2[((size_t)(cap * 2 + (d >> 2)) * 128 + b) * 4 + (d & 3)]
            = vals[r] * nr / (1.f + n2[r]);
    }
}

// ---------------- zsum: zsum[i,b] = sum_o exp(blog[o,i,b])  (no max — blog bounded)
__global__ __launch_bounds__(128) void zsum_kernel(
    const float* __restrict__ blog, float* __restrict__ zsum) {
    int i = blockIdx.x;
    int b = threadIdx.x;
    const float* src = blog + (size_t)i * 128 + b;
    float sum = 0.f;
    #pragma unroll
    for (int o = 0; o < 64; ++o) sum += __expf(src[(size_t)o * 98304]);
    zsum[i * 128 + b] = sum;
}

// ---------------- s-pass: W staged in LDS; u/blog pipelined 3-deep.
// c = exp(blog)/zsum. 2-term MFMA: W split (hi+lo), c*u truncated.
template <bool UNIFORM>
__global__ __launch_bounds__(256, 4) void spass_kernel(
    const float* __restrict__ W, const float* __restrict__ u2,
    const float* __restrict__ blog, const float* __restrict__ zsum,
    float* __restrict__ s_part) {
    int o = blockIdx.x;
    int it = blockIdx.y;       // 0..23 (32 caps)
    int tid = threadIdx.x;
    int wv = tid >> 6;
    int l = tid & 63;
    int q = l >> 4, r16 = l & 15;
    int i0 = it * 32;
    __shared__ float wl[32 * 132];

    float4 ua[3][2][2];
    float blv[3][2], zv[3][2];
    auto issue = [&](int s, int buf) {
        int cap = i0 + s * 4 + q;
        #pragma unroll
        for (int m = 0; m < 2; ++m) {
            int b = wv * 32 + m * 16 + r16;
            ua[buf][m][0] = *(const float4*)(u2 + ((size_t)(cap * 2 + 0) * 128 + b) * 4);
            ua[buf][m][1] = *(const float4*)(u2 + ((size_t)(cap * 2 + 1) * 128 + b) * 4);
            if (!UNIFORM) {
                blv[buf][m] = blog[((size_t)o * 768 + cap) * 128 + b];
                zv[buf][m]  = zsum[cap * 128 + b];
            }
        }
    };

    issue(0, 0);
    issue(1, 1);
    #pragma unroll
    for (int itr = 0; itr < 4; ++itr) {
        int F = tid + 256 * itr;
        int cap = F >> 5, slot = F & 31;
        *(float4*)(wl + cap * 132 + slot * 4) =
            *(const float4*)(W + ((size_t)(i0 + cap) * 64 + o) * 128 + slot * 4);
    }
    __syncthreads();

    f32x4 acc0 = {0.f, 0.f, 0.f, 0.f};
    f32x4 acc1 = {0.f, 0.f, 0.f, 0.f};
    #pragma unroll
    for (int s = 0; s < 8; ++s) {
        int cur = s % 3;
        if (s < 6) issue(s + 2, (s + 2) % 3);
        const float* wp = wl + (s * 4 + q) * 132 + r16 * 8;
        float wv8[8];
        *(float4*)(wv8) = *(const float4*)wp;
        *(float4*)(wv8 + 4) = *(const float4*)(wp + 4);
        bfrag bhi, blo;
        split8(wv8, bhi, blo);
        #pragma unroll
        for (int m = 0; m < 2; ++m) {
            float uv[8];
            *(float4*)(uv) = ua[cur][m][0];
            *(float4*)(uv + 4) = ua[cur][m][1];
            if (!UNIFORM) {
                float c = __expf(blv[cur][m]) / zv[cur][m];
                #pragma unroll
                for (int j = 0; j < 8; ++j) uv[j] *= c;
            }
            bfrag ahi;
            trunc8(uv, ahi);
            if (m == 0) {
                acc0 = __builtin_amdgcn_mfma_f32_16x16x32_bf16(ahi, bhi, acc0, 0, 0, 0);
                acc0 = __builtin_amdgcn_mfma_f32_16x16x32_bf16(ahi, blo, acc0, 0, 0, 0);
            } else {
                acc1 = __builtin_amdgcn_mfma_f32_16x16x32_bf16(ahi, bhi, acc1, 0, 0, 0);
                acc1 = __builtin_amdgcn_mfma_f32_16x16x32_bf16(ahi, blo, acc1, 0, 0, 0);
            }
        }
    }
    #pragma unroll
    for (int reg = 0; reg < 4; ++reg) {
        int b0 = wv * 32 + q * 4 + reg;
        s_part[(((size_t)it * 128 + b0) * 64 + o) * 16 + r16] = acc0[reg];
        s_part[(((size_t)it * 128 + b0 + 16) * 64 + o) * 16 + r16] = acc1[reg];
    }
}

// ---------------- reduce partials + squash -> v ([b][o][k] or [o][b][k])
template <bool TRANSPOSED>
__global__ __launch_bounds__(256) void squashv_kernel(
    const float* __restrict__ s_part, float* __restrict__ v, float scale) {
    int idx = blockIdx.x * 256 + threadIdx.x;
    float acc = 0.f;
    #pragma unroll
    for (int it = 0; it < 24; ++it) acc += s_part[(size_t)it * 131072 + idx];
    acc *= scale;
    float n2 = acc * acc;
    n2 += __shfl_xor(n2, 1, 64);
    n2 += __shfl_xor(n2, 2, 64);
    n2 += __shfl_xor(n2, 4, 64);
    n2 += __shfl_xor(n2, 8, 64);
    float n = sqrtf(n2);
    float val = acc * n / (1.f + n2);
    if (TRANSPOSED) {
        int k = idx & 15, o = (idx >> 4) & 63, b = idx >> 10;
        v[((size_t)o * 128 + b) * 16 + k] = val;
    } else {
        v[idx] = val;
    }
}

// ---------------- b-pass: blog (+)= sum_d u*(W x v); plain stores (no atomics)
template <bool ACCUM>
__global__ __launch_bounds__(256, 4) void bpass_kernel(
    const float* __restrict__ W, const float* __restrict__ u2,
    const float* __restrict__ v_t, float* __restrict__ blog) {
    int o = blockIdx.x, it = blockIdx.y;   // it: 0..23 (32 caps)
    int tid = threadIdx.x;
    int wv = tid >> 6;
    int l = tid & 63;
    int r = l & 31;
    int kh = l >> 5;
    int capB = it * 32;
    __shared__ float wl[32 * 164];
    #pragma unroll
    for (int itr = 0; itr < 4; ++itr) {
        int F = tid + 256 * itr;
        int cap = F >> 5, slot = F & 31;
        int k = slot >> 1, dh = slot & 1;
        float4 t4 = *(const float4*)(W + ((size_t)(capB + cap) * 64 + o) * 128 + k * 8 + dh * 4);
        float* dst = wl + cap * 164 + (dh * 4) * 20 + k;
        dst[0] = t4.x; dst[20] = t4.y; dst[40] = t4.z; dst[60] = t4.w;
    }
    bfrag vhi[4], vlo[4];
    #pragma unroll
    for (int nt = 0; nt < 4; ++nt) {
        const float* vp = v_t + ((size_t)o * 128 + nt * 32 + r) * 16 + kh * 8;
        float vv8[8];
        *(float4*)(vv8) = *(const float4*)vp;
        *(float4*)(vv8 + 4) = *(const float4*)(vp + 4);
        split8(vv8, vhi[nt], vlo[nt]);
    }
    __syncthreads();
    #pragma unroll
    for (int mt = 0; mt < 2; ++mt) {
        int cl = wv * 8 + mt * 4 + (r >> 3);
        const float* ap = wl + cl * 164 + (r & 7) * 20 + kh * 8;
        float a8[8];
        *(float4*)(a8) = *(const float4*)ap;
        *(float4*)(a8 + 4) = *(const float4*)(ap + 4);
        int capg = capB + wv * 8 + mt * 4;
        int gw = kh * 2;
        float prevv[4][2];
        if (ACCUM) {
            #pragma unroll
            for (int nt = 0; nt < 4; ++nt) {
                int b = nt * 32 + r;
                #pragma unroll
                for (int gg = 0; gg < 2; ++gg)
                    prevv[nt][gg] = blog[((size_t)o * 768 + capg + gw + gg) * 128 + b];
            }
        }
        float4 u4b[2][4];
        #pragma unroll
        for (int g = 0; g < 4; ++g)
            u4b[0][g] = *(const float4*)(u2 + ((size_t)((capg + g) * 2 + kh) * 128 + r) * 4);
        bfrag ahi, alo;
        split8(a8, ahi, alo);
        #pragma unroll
        for (int nt = 0; nt < 4; ++nt) {
            int cur = nt & 1;
            if (nt < 3) {
                int bn = (nt + 1) * 32 + r;
                #pragma unroll
                for (int g = 0; g < 4; ++g)
                    u4b[cur ^ 1][g] = *(const float4*)(u2 + ((size_t)((capg + g) * 2 + kh) * 128 + bn) * 4);
            }
            int b = nt * 32 + r;
            f32x16 acc;
            #pragma unroll
            for (int z = 0; z < 16; ++z) acc[z] = 0.f;
            acc = __builtin_amdgcn_mfma_f32_32x32x16_bf16(ahi, vhi[nt], acc, 0, 0, 0);
            acc = __builtin_amdgcn_mfma_f32_32x32x16_bf16(ahi, vlo[nt], acc, 0, 0, 0);
            acc = __builtin_amdgcn_mfma_f32_32x32x16_bf16(alo, vhi[nt], acc, 0, 0, 0);
            float full[4];
            #pragma unroll
            for (int g = 0; g < 4; ++g) {
                float part = u4b[cur][g].x * acc[g * 4 + 0] + u4b[cur][g].y * acc[g * 4 + 1]
                           + u4b[cur][g].z * acc[g * 4 + 2] + u4b[cur][g].w * acc[g * 4 + 3];
                full[g] = part + __shfl_xor(part, 32, 64);
            }
            #pragma unroll
            for (int gg = 0; gg < 2; ++gg) {
                int g = gw + gg;
                size_t bi = ((size_t)o * 768 + capg + g) * 128 + b;
                blog[bi] = (ACCUM ? prevv[nt][gg] : 0.f) + full[g];
            }
        }
    }
}

extern "C" void kernel_launch(void* const* d_in, const int* in_sizes, int n_in,
                              void* d_out, int out_size, void* d_ws, size_t ws_size,
                              hipStream_t stream) {
    const float* x  = (const float*)d_in[0];
    const float* w1 = (const float*)d_in[1];
    const float* b1 = (const float*)d_in[2];
    const float* wp = (const float*)d_in[3];
    const float* bp = (const float*)d_in[4];
    const float* W  = (const float*)d_in[5];
    float* out = (float*)d_out;
    float* ws = (float*)d_ws;

    float* u2     = ws;                  // 786432
    float* blog   = ws + 786432;         // 6291456
    float* zsum   = ws + 7077888;        // 98304
    float* v      = ws + 7274496;        // 131072
    float* s_part = ws + 7405568;        // 24 * 131072
    float* B2     = s_part;              // 884736, dead before spass writes s_part

    front_kernel<<<128, 256, 0, stream>>>(x, w1, b1, B2);
    pc_gemm_kernel<<<dim3(192, 4), 256, 0, stream>>>(wp, bp, B2, u2);

    // iteration 0: c uniform (1/64 folded into squash scale)
    spass_kernel<true><<<dim3(64, 24), 256, 0, stream>>>(W, u2, nullptr, nullptr, s_part);
    squashv_kernel<true><<<512, 256, 0, stream>>>(s_part, v, 1.f / 64.f);
    bpass_kernel<false><<<dim3(64, 24), 256, 0, stream>>>(W, u2, v, blog);

    // iteration 1
    zsum_kernel<<<768, 128, 0, stream>>>(blog, zsum);
    spass_kernel<false><<<dim3(64, 24), 256, 0, stream>>>(W, u2, blog, zsum, s_part);
    squashv_kernel<true><<<512, 256, 0, stream>>>(s_part, v, 1.f);
    bpass_kernel<true><<<dim3(64, 24), 256, 0, stream>>>(W, u2, v, blog);

    // final
    zsum_kernel<<<768, 128, 0, stream>>>(blog, zsum);
    spass_kernel<false><<<dim3(64, 24), 256, 0, stream>>>(W, u2, blog, zsum, s_part);
    squashv_kernel<false><<<512, 256, 0, stream>>>(s_part, out, 1.f);
}

// Round 15
// 141.116 us; speedup vs baseline: 11.2270x; 1.0265x over previous
//
#include <hip/hip_runtime.h>
#include <math.h>

typedef __attribute__((ext_vector_type(8))) short bfrag;    // 8 bf16 = 4 VGPR
typedef __attribute__((ext_vector_type(4))) float f32x4;    // 16x16 accumulator
typedef __attribute__((ext_vector_type(16))) float f32x16;  // 32x32 accumulator
typedef __attribute__((ext_vector_type(4))) unsigned short ushort4v;

// split 8 f32 into bf16 hi + lo; (hh+hl+lh) ~ fp32. trunc8: hi only (~2^-9 rel).
__device__ __forceinline__ void split8(const float* x, bfrag& hi, bfrag& lo) {
    #pragma unroll
    for (int j = 0; j < 8; ++j) {
        unsigned xb = __float_as_uint(x[j]);
        unsigned hb = xb & 0xffff0000u;
        float lf = x[j] - __uint_as_float(hb);
        hi[j] = (short)(xb >> 16);
        lo[j] = (short)(__float_as_uint(lf) >> 16);
    }
}
__device__ __forceinline__ void trunc8(const float* x, bfrag& hi) {
    #pragma unroll
    for (int j = 0; j < 8; ++j) hi[j] = (short)(__float_as_uint(x[j]) >> 16);
}

// ---------------- front: conv1 + im2col fused, one block per batch element.
__global__ __launch_bounds__(256) void front_kernel(
    const float* __restrict__ x, const float* __restrict__ w1,
    const float* __restrict__ b1, float* __restrict__ B2) {
    __shared__ float xl[4032];
    __shared__ float wl[3456];
    __shared__ float hl[3744];
    int b = blockIdx.x, tid = threadIdx.x;
    const float* xb = x + (size_t)b * 4032;
    #pragma unroll
    for (int i = 0; i < 4; ++i) {
        int idx = tid + 256 * i;
        if (idx < 1008) *(float4*)(xl + idx * 4) = *(const float4*)(xb + idx * 4);
        if (idx < 864)  *(float4*)(wl + idx * 4) = *(const float4*)(w1 + idx * 4);
    }
    __syncthreads();
    for (int idx = tid; idx < 3744; idx += 256) {
        int oc = idx / 117, r = idx % 117;
        int oh = r / 13, ow = r % 13;
        float acc = b1[oc];
        #pragma unroll
        for (int ic = 0; ic < 3; ++ic) {
            const float* xc = xl + ic * 1344 + (oh * 3) * 42 + ow * 3;
            const float* wc = wl + (oc * 3 + ic) * 36;
            #pragma unroll
            for (int kh = 0; kh < 6; ++kh)
                #pragma unroll
                for (int kw = 0; kw < 6; ++kw)
                    acc += xc[kh * 42 + kw] * wc[kh * 6 + kw];
        }
        hl[idx] = fmaxf(acc, 0.f);
    }
    __syncthreads();
    for (int f = tid; f < 864; f += 256) {     // (ko, s)
        int ko = f / 24, s = f % 24;
        int h = s / 6, w = s % 6;
        float o8[8];
        #pragma unroll
        for (int j = 0; j < 8; ++j) {
            int k = ko * 8 + j;
            int ic = k / 9, rr = k % 9;
            int kh = rr / 3, kw = rr % 3;
            o8[j] = hl[ic * 117 + (2 * h + kh) * 13 + (2 * w + kw)];
        }
        float* dst = B2 + ((size_t)ko * 3072 + b * 24 + s) * 8;
        *(float4*)dst = *(const float4*)o8;
        *(float4*)(dst + 4) = *(const float4*)(o8 + 4);
    }
}

// ---------------- pc GEMM (MFMA) + bias + squash -> u2[i][dh][b][4]
__global__ __launch_bounds__(256) void pc_gemm_kernel(
    const float* __restrict__ wpc, const float* __restrict__ bias,
    const float* __restrict__ B2, float* __restrict__ u2) {
    int wv = threadIdx.x >> 6;
    int l = threadIdx.x & 63;
    int q = l >> 4, r16 = l & 15;
    int c2t = blockIdx.y * 4 + wv;
    int n0 = blockIdx.x * 16;
    f32x4 acc = {0.f, 0.f, 0.f, 0.f};
    const float* ap0 = wpc + (size_t)(c2t * 16 + r16) * 288 + q * 8;
    const float* bp0 = B2 + ((size_t)q * 3072 + n0 + r16) * 8;
    #pragma unroll
    for (int ks = 0; ks < 9; ++ks) {
        float av[8], bv[8];
        *(float4*)av = *(const float4*)(ap0 + ks * 32);
        *(float4*)(av + 4) = *(const float4*)(ap0 + ks * 32 + 4);
        *(float4*)bv = *(const float4*)(bp0 + (size_t)ks * 98304);
        *(float4*)(bv + 4) = *(const float4*)(bp0 + (size_t)ks * 98304 + 4);
        bfrag ahi, alo, bhi, blo;
        split8(av, ahi, alo);
        split8(bv, bhi, blo);
        acc = __builtin_amdgcn_mfma_f32_16x16x32_bf16(ahi, bhi, acc, 0, 0, 0);
        acc = __builtin_amdgcn_mfma_f32_16x16x32_bf16(ahi, blo, acc, 0, 0, 0);
        acc = __builtin_amdgcn_mfma_f32_16x16x32_bf16(alo, bhi, acc, 0, 0, 0);
    }
    int n = n0 + r16;
    int b = n / 24, s = n % 24;
    float vals[4], n2[4];
    #pragma unroll
    for (int r = 0; r < 4; ++r) {
        float xv = acc[r] + bias[c2t * 16 + q * 4 + r];
        vals[r] = xv;
        n2[r] = xv * xv;
    }
    #pragma unroll
    for (int r = 0; r < 4; ++r) {
        n2[r] += __shfl_xor(n2[r], 1, 64);
        n2[r] += __shfl_xor(n2[r], 2, 64);
        n2[r] += __shfl_xor(n2[r], 4, 64);
    }
    #pragma unroll
    for (int r = 0; r < 4; ++r) {
        int c2 = c2t * 16 + q * 4 + r;
        int cap = c2 * 3 + (s >> 3);
        int d = s & 7;
        float nr = sqrtf(n2[r]);
        u2[((size_t)(cap * 2 + (d >> 2)) * 128 + b) * 4 + (d & 3)]
            = vals[r] * nr / (1.f + n2[r]);
    }
}

// ---------------- zsum: zsum[i,b] = sum_o exp(blog[o,i,b])  (no max — blog bounded)
__global__ __launch_bounds__(128) void zsum_kernel(
    const float* __restrict__ blog, float* __restrict__ zsum) {
    int i = blockIdx.x;
    int b = threadIdx.x;
    const float* src = blog + (size_t)i * 128 + b;
    float sum = 0.f;
    #pragma unroll
    for (int o = 0; o < 64; ++o) sum += __expf(src[(size_t)o * 98304]);
    zsum[i * 128 + b] = sum;
}

// ---------------- s-pass: 64-cap tiles; W pre-split to bf16 hi/lo in LDS
// (per-step W cost = 2x ds_read_b128, zero VALU). u/blog pipelined 3-deep.
// c = exp(blog)/zsum. 2-term MFMA: W (hi+lo), c*u truncated.
template <bool UNIFORM>
__global__ __launch_bounds__(256, 4) void spass_kernel(
    const float* __restrict__ W, const float* __restrict__ u2,
    const float* __restrict__ blog, const float* __restrict__ zsum,
    float* __restrict__ s_part) {
    int o = blockIdx.x;
    int it = blockIdx.y;       // 0..11 (64 caps)
    int tid = threadIdx.x;
    int wv = tid >> 6;
    int l = tid & 63;
    int q = l >> 4, r16 = l & 15;
    int i0 = it * 64;
    __shared__ unsigned short whi[64 * 136];   // bf16 hi, pitch 136 (<=2-way conflicts)
    __shared__ unsigned short wlo[64 * 136];   // bf16 lo

    float4 ua[3][2][2];
    float blv[3][2], zv[3][2];
    auto issue = [&](int s, int buf) {
        int cap = i0 + s * 4 + q;
        #pragma unroll
        for (int m = 0; m < 2; ++m) {
            int b = wv * 32 + m * 16 + r16;
            ua[buf][m][0] = *(const float4*)(u2 + ((size_t)(cap * 2 + 0) * 128 + b) * 4);
            ua[buf][m][1] = *(const float4*)(u2 + ((size_t)(cap * 2 + 1) * 128 + b) * 4);
            if (!UNIFORM) {
                blv[buf][m] = blog[((size_t)o * 768 + cap) * 128 + b];
                zv[buf][m]  = zsum[cap * 128 + b];
            }
        }
    };

    issue(0, 0);
    issue(1, 1);
    // stage W tile: 64 caps x 128 floats, coalesced; split to bf16 hi/lo on the fly
    #pragma unroll
    for (int itr = 0; itr < 8; ++itr) {
        int F = tid + 256 * itr;     // 0..2047 float4s
        int cap = F >> 5, slot = F & 31;
        float4 t4 = *(const float4*)(W + ((size_t)(i0 + cap) * 64 + o) * 128 + slot * 4);
        ushort4v h4, l4;
        float tf[4] = {t4.x, t4.y, t4.z, t4.w};
        #pragma unroll
        for (int j = 0; j < 4; ++j) {
            unsigned xb = __float_as_uint(tf[j]);
            float lf = tf[j] - __uint_as_float(xb & 0xffff0000u);
            h4[j] = (unsigned short)(xb >> 16);
            l4[j] = (unsigned short)(__float_as_uint(lf) >> 16);
        }
        *(ushort4v*)(whi + cap * 136 + slot * 4) = h4;
        *(ushort4v*)(wlo + cap * 136 + slot * 4) = l4;
    }
    __syncthreads();

    f32x4 acc0 = {0.f, 0.f, 0.f, 0.f};
    f32x4 acc1 = {0.f, 0.f, 0.f, 0.f};
    #pragma unroll
    for (int s = 0; s < 16; ++s) {
        int cur = s % 3;
        if (s < 14) issue(s + 2, (s + 2) % 3);
        int wrow = (s * 4 + q) * 136 + r16 * 8;
        bfrag bhi = *(const bfrag*)(whi + wrow);
        bfrag blo = *(const bfrag*)(wlo + wrow);
        #pragma unroll
        for (int m = 0; m < 2; ++m) {
            float uv[8];
            *(float4*)(uv) = ua[cur][m][0];
            *(float4*)(uv + 4) = ua[cur][m][1];
            if (!UNIFORM) {
                float c = __expf(blv[cur][m]) / zv[cur][m];
                #pragma unroll
                for (int j = 0; j < 8; ++j) uv[j] *= c;
            }
            bfrag ahi;
            trunc8(uv, ahi);
            if (m == 0) {
                acc0 = __builtin_amdgcn_mfma_f32_16x16x32_bf16(ahi, bhi, acc0, 0, 0, 0);
                acc0 = __builtin_amdgcn_mfma_f32_16x16x32_bf16(ahi, blo, acc0, 0, 0, 0);
            } else {
                acc1 = __builtin_amdgcn_mfma_f32_16x16x32_bf16(ahi, bhi, acc1, 0, 0, 0);
                acc1 = __builtin_amdgcn_mfma_f32_16x16x32_bf16(ahi, blo, acc1, 0, 0, 0);
            }
        }
    }
    #pragma unroll
    for (int reg = 0; reg < 4; ++reg) {
        int b0 = wv * 32 + q * 4 + reg;
        s_part[(((size_t)it * 128 + b0) * 64 + o) * 16 + r16] = acc0[reg];
        s_part[(((size_t)it * 128 + b0 + 16) * 64 + o) * 16 + r16] = acc1[reg];
    }
}

// ---------------- reduce 12 partials + squash -> v ([b][o][k] or [o][b][k])
template <bool TRANSPOSED>
__global__ __launch_bounds__(256) void squashv_kernel(
    const float* __restrict__ s_part, float* __restrict__ v, float scale) {
    int idx = blockIdx.x * 256 + threadIdx.x;
    float acc = 0.f;
    #pragma unroll
    for (int it = 0; it < 12; ++it) acc += s_part[(size_t)it * 131072 + idx];
    acc *= scale;
    float n2 = acc * acc;
    n2 += __shfl_xor(n2, 1, 64);
    n2 += __shfl_xor(n2, 2, 64);
    n2 += __shfl_xor(n2, 4, 64);
    n2 += __shfl_xor(n2, 8, 64);
    float n = sqrtf(n2);
    float val = acc * n / (1.f + n2);
    if (TRANSPOSED) {
        int k = idx & 15, o = (idx >> 4) & 63, b = idx >> 10;
        v[((size_t)o * 128 + b) * 16 + k] = val;
    } else {
        v[idx] = val;
    }
}

// ---------------- b-pass: blog (+)= sum_d u*(W x v); plain stores
template <bool ACCUM>
__global__ __launch_bounds__(256, 4) void bpass_kernel(
    const float* __restrict__ W, const float* __restrict__ u2,
    const float* __restrict__ v_t, float* __restrict__ blog) {
    int o = blockIdx.x, it = blockIdx.y;   // it: 0..23 (32 caps)
    int tid = threadIdx.x;
    int wv = tid >> 6;
    int l = tid & 63;
    int r = l & 31;
    int kh = l >> 5;
    int capB = it * 32;
    __shared__ float wl[32 * 164];
    #pragma unroll
    for (int itr = 0; itr < 4; ++itr) {
        int F = tid + 256 * itr;
        int cap = F >> 5, slot = F & 31;
        int k = slot >> 1, dh = slot & 1;
        float4 t4 = *(const float4*)(W + ((size_t)(capB + cap) * 64 + o) * 128 + k * 8 + dh * 4);
        float* dst = wl + cap * 164 + (dh * 4) * 20 + k;
        dst[0] = t4.x; dst[20] = t4.y; dst[40] = t4.z; dst[60] = t4.w;
    }
    bfrag vhi[4], vlo[4];
    #pragma unroll
    for (int nt = 0; nt < 4; ++nt) {
        const float* vp = v_t + ((size_t)o * 128 + nt * 32 + r) * 16 + kh * 8;
        float vv8[8];
        *(float4*)(vv8) = *(const float4*)vp;
        *(float4*)(vv8 + 4) = *(const float4*)(vp + 4);
        split8(vv8, vhi[nt], vlo[nt]);
    }
    __syncthreads();
    #pragma unroll
    for (int mt = 0; mt < 2; ++mt) {
        int cl = wv * 8 + mt * 4 + (r >> 3);
        const float* ap = wl + cl * 164 + (r & 7) * 20 + kh * 8;
        float a8[8];
        *(float4*)(a8) = *(const float4*)ap;
        *(float4*)(a8 + 4) = *(const float4*)(ap + 4);
        int capg = capB + wv * 8 + mt * 4;
        int gw = kh * 2;
        float prevv[4][2];
        if (ACCUM) {
            #pragma unroll
            for (int nt = 0; nt < 4; ++nt) {
                int b = nt * 32 + r;
                #pragma unroll
                for (int gg = 0; gg < 2; ++gg)
                    prevv[nt][gg] = blog[((size_t)o * 768 + capg + gw + gg) * 128 + b];
            }
        }
        float4 u4b[2][4];
        #pragma unroll
        for (int g = 0; g < 4; ++g)
            u4b[0][g] = *(const float4*)(u2 + ((size_t)((capg + g) * 2 + kh) * 128 + r) * 4);
        bfrag ahi, alo;
        split8(a8, ahi, alo);
        #pragma unroll
        for (int nt = 0; nt < 4; ++nt) {
            int cur = nt & 1;
            if (nt < 3) {
                int bn = (nt + 1) * 32 + r;
                #pragma unroll
                for (int g = 0; g < 4; ++g)
                    u4b[cur ^ 1][g] = *(const float4*)(u2 + ((size_t)((capg + g) * 2 + kh) * 128 + bn) * 4);
            }
            int b = nt * 32 + r;
            f32x16 acc;
            #pragma unroll
            for (int z = 0; z < 16; ++z) acc[z] = 0.f;
            acc = __builtin_amdgcn_mfma_f32_32x32x16_bf16(ahi, vhi[nt], acc, 0, 0, 0);
            acc = __builtin_amdgcn_mfma_f32_32x32x16_bf16(ahi, vlo[nt], acc, 0, 0, 0);
            acc = __builtin_amdgcn_mfma_f32_32x32x16_bf16(alo, vhi[nt], acc, 0, 0, 0);
            float full[4];
            #pragma unroll
            for (int g = 0; g < 4; ++g) {
                float part = u4b[cur][g].x * acc[g * 4 + 0] + u4b[cur][g].y * acc[g * 4 + 1]
                           + u4b[cur][g].z * acc[g * 4 + 2] + u4b[cur][g].w * acc[g * 4 + 3];
                full[g] = part + __shfl_xor(part, 32, 64);
            }
            #pragma unroll
            for (int gg = 0; gg < 2; ++gg) {
                int g = gw + gg;
                size_t bi = ((size_t)o * 768 + capg + g) * 128 + b;
                blog[bi] = (ACCUM ? prevv[nt][gg] : 0.f) + full[g];
            }
        }
    }
}

extern "C" void kernel_launch(void* const* d_in, const int* in_sizes, int n_in,
                              void* d_out, int out_size, void* d_ws, size_t ws_size,
                              hipStream_t stream) {
    const float* x  = (const float*)d_in[0];
    const float* w1 = (const float*)d_in[1];
    const float* b1 = (const float*)d_in[2];
    const float* wp = (const float*)d_in[3];
    const float* bp = (const float*)d_in[4];
    const float* W  = (const float*)d_in[5];
    float* out = (float*)d_out;
    float* ws = (float*)d_ws;

    float* u2     = ws;                  // 786432
    float* blog   = ws + 786432;         // 6291456
    float* zsum   = ws + 7077888;        // 98304
    float* v      = ws + 7274496;        // 131072
    float* s_part = ws + 7405568;        // 12 * 131072
    float* B2     = s_part;              // 884736, dead before spass writes s_part

    front_kernel<<<128, 256, 0, stream>>>(x, w1, b1, B2);
    pc_gemm_kernel<<<dim3(192, 4), 256, 0, stream>>>(wp, bp, B2, u2);

    // iteration 0: c uniform (1/64 folded into squash scale)
    spass_kernel<true><<<dim3(64, 12), 256, 0, stream>>>(W, u2, nullptr, nullptr, s_part);
    squashv_kernel<true><<<512, 256, 0, stream>>>(s_part, v, 1.f / 64.f);
    bpass_kernel<false><<<dim3(64, 24), 256, 0, stream>>>(W, u2, v, blog);

    // iteration 1
    zsum_kernel<<<768, 128, 0, stream>>>(blog, zsum);
    spass_kernel<false><<<dim3(64, 12), 256, 0, stream>>>(W, u2, blog, zsum, s_part);
    squashv_kernel<true><<<512, 256, 0, stream>>>(s_part, v, 1.f);
    bpass_kernel<true><<<dim3(64, 24), 256, 0, stream>>>(W, u2, v, blog);

    // final
    zsum_kernel<<<768, 128, 0, stream>>>(blog, zsum);
    spass_kernel<false><<<dim3(64, 12), 256, 0, stream>>>(W, u2, blog, zsum, s_part);
    squashv_kernel<false><<<512, 256, 0, stream>>>(s_part, out, 1.f);
}